// Round 16
// baseline (86.971 us; speedup 1.0000x reference)
//
#include <hip/hip_runtime.h>
#include <cfloat>

#define TOKENS 16384   // B*N
#define DDIM   2048
#define NEXP   128
#define KTOP   8
#define MB     64      // tokens per block
#define CH     64      // k elements per chunk
#define NCH    (DDIM / CH)   // 32
#define NTHR   512     // 8 waves = 4 token-groups x 2 expert-halves

typedef float    f32x4 __attribute__((ext_vector_type(4)));
typedef _Float16 f16x8 __attribute__((ext_vector_type(8)));

// W fragment tables in d_ws (rebuilt each launch):
//   WFH[((eb*NCH + c)*2 + ks)*64 + lane] : uint4 = 8 fp16  wh = fp16(w)
//   WFM = WFH + WFRAG_N                 : 8 fp16  wm = fp16((w - wh)*4096)
// Slot j of lane l holds k = c*64 + ks*32 + (l>>4)*8 + j, expert = eb*16 + (l&15).
#define WFRAG_N (8 * NCH * 2 * 64)   // 32768 uint4 per table (512 KB)

__device__ __forceinline__ unsigned short f16bits(float f) {
    _Float16 h = (_Float16)f;                      // RNE
    return __builtin_bit_cast(unsigned short, h);
}
__device__ __forceinline__ float f16tof(unsigned short u) {
    return (float)__builtin_bit_cast(_Float16, u); // exact
}

__global__ __launch_bounds__(256, 1) void wfrag_kernel(
    const float* __restrict__ W, uint4* __restrict__ wf)
{
    int id   = blockIdx.x * 256 + threadIdx.x;   // 0..32767
    int lane = id & 63;
    int ks   = (id >> 6) & 1;
    int c    = (id >> 7) & (NCH - 1);
    int eb   = id >> 12;
    int e    = eb * 16 + (lane & 15);
    int k0   = c * CH + ks * 32 + (lane >> 4) * 8;
    const float* src = W + (size_t)e * DDIM + k0;
    unsigned hw[4], mw[4];
#pragma unroll
    for (int p = 0; p < 4; ++p) {
        float f0 = src[2 * p], f1 = src[2 * p + 1];
        unsigned short h0 = f16bits(f0), h1 = f16bits(f1);
        unsigned short m0 = f16bits((f0 - f16tof(h0)) * 4096.0f);
        unsigned short m1 = f16bits((f1 - f16tof(h1)) * 4096.0f);
        hw[p] = (unsigned)h0 | ((unsigned)h1 << 16);
        mw[p] = (unsigned)m0 | ((unsigned)m1 << 16);
    }
    wf[id]           = make_uint4(hw[0], hw[1], hw[2], hw[3]);
    wf[WFRAG_N + id] = make_uint4(mw[0], mw[1], mw[2], mw[3]);
}

// branchless sorted-insert into descending top-8 list.
// strict '>' => ties keep the earlier (lower) index, matching jax.lax.top_k.
__device__ __forceinline__ void insert8(float (&vals)[8], int (&idxs)[8], float v, int e) {
    bool c[8];
#pragma unroll
    for (int p = 0; p < 8; ++p) c[p] = v > vals[p];
#pragma unroll
    for (int p = 7; p >= 1; --p) {
        vals[p] = c[p] ? (c[p - 1] ? vals[p - 1] : v) : vals[p];
        idxs[p] = c[p] ? (c[p - 1] ? idxs[p - 1] : e) : idxs[p];
    }
    vals[0] = c[0] ? v : vals[0];
    idxs[0] = c[0] ? e : idxs[0];
}

// BARRIER-FREE fp16-split MFMA router. R10-R15 (6 schedules, 62-68us, all
// pipes <=20%) => the binder is the block-wide barrier lockstep itself, not
// any phase cost (m233 signature). This round deletes the mechanism: the
// MFMA A-fragment is 16B of k-contiguous x per lane, loaded DIRECTLY from
// global (2 float4 per ks) and split to fp16 h/m in registers. Wave owns
// 16 tok x 64 exp; x, W both per-wave from global; ZERO LDS / ZERO barriers
// in the K-loop -> waves free-run, pipes overlap by construction.
// Same (l>>4,j)->k map, same chunk->ks->3-pass order, same fmaf merge ->
// logits bit-identical to R10-R15 -> indices identical.
__global__ __launch_bounds__(NTHR, 1) void router_kernel(
    const float* __restrict__ x, const uint4* __restrict__ wf,
    const float* __restrict__ b, float* __restrict__ out_gates,
    float* __restrict__ out_idx)
{
    // LDS used ONLY by the epilogue: lg [64][132] f32; plv/pli [512][8]
    __shared__ __align__(16) char smem[66560];
    float* lg  = (float*)smem;
    float* plv = (float*)(smem + 33792);
    int*   pli = (int*)(smem + 50176);

    const int tid  = threadIdx.x;
    const int lane = tid & 63;
    const int wid  = tid >> 6;           // wave 0..7
    const int tg   = wid >> 1;           // token group: rows tg*16..tg*16+15
    const int eh   = wid & 1;            // expert half: experts eh*64..eh*64+63
    const int tok0 = blockIdx.x * MB;

    const uint4* WFH = wf;
    const uint4* WFM = wf + WFRAG_N;

    f32x4 acc1[4], acc2[4];              // [nf] -> experts eh*64+nf*16+..
#pragma unroll
    for (int nf = 0; nf < 4; ++nf) {
        acc1[nf] = (f32x4){0.f, 0.f, 0.f, 0.f};
        acc2[nf] = (f32x4){0.f, 0.f, 0.f, 0.f};
    }

    const float4* x4 = (const float4*)x;
    // per-lane x row base (float4 units): row = tok0 + tg*16 + (lane&15)
    const size_t xrow4 = (size_t)(tok0 + tg * 16 + (lane & 15)) * (DDIM / 4);
    const int    xsub  = (lane >> 4) * 2;   // float4 offset within k-octet pair

    // A-fragment x loads for chunk c: [ks*2+half] = x4[xrow4 + c*16 + ks*8 + xsub + half]
    auto loadX = [&](int c, float4 (&xr)[4]) {
#pragma unroll
        for (int ks = 0; ks < 2; ++ks)
#pragma unroll
            for (int h = 0; h < 2; ++h)
                xr[ks * 2 + h] = x4[xrow4 + (size_t)c * 16 + ks * 8 + xsub + h];
    };
    // split 8 fp32 -> fp16 hi fragment + scaled-residual fragment
    auto packX = [&](const float4& a, const float4& bq, f16x8& ah, f16x8& am) {
        float v[8] = {a.x, a.y, a.z, a.w, bq.x, bq.y, bq.z, bq.w};
        unsigned short hb[8], mb[8];
#pragma unroll
        for (int i = 0; i < 8; ++i) {
            hb[i] = f16bits(v[i]);
            mb[i] = f16bits((v[i] - f16tof(hb[i])) * 4096.0f);
        }
#pragma unroll
        for (int i = 0; i < 8; ++i) {
            ah[i] = __builtin_bit_cast(_Float16, hb[i]);
            am[i] = __builtin_bit_cast(_Float16, mb[i]);
        }
    };

    auto computeChunk = [&](int c, const float4 (&xr)[4]) {
        // W fragments for this chunk (16 uint4; L2-resident table)
        uint4 wreg[16];   // [ks*8 + nf*2 + (0=h,1=m)]
#pragma unroll
        for (int ks = 0; ks < 2; ++ks)
#pragma unroll
            for (int nf = 0; nf < 4; ++nf) {
                int idx = (((eh * 4 + nf) * NCH + c) * 2 + ks) * 64 + lane;
                wreg[ks * 8 + nf * 2]     = WFH[idx];
                wreg[ks * 8 + nf * 2 + 1] = WFM[idx];
            }
#pragma unroll
        for (int ks = 0; ks < 2; ++ks) {
            f16x8 ah, am;
            packX(xr[ks * 2], xr[ks * 2 + 1], ah, am);
            __builtin_amdgcn_s_setprio(1);
#pragma unroll
            for (int nf = 0; nf < 4; ++nf) {
                f16x8 wh = __builtin_bit_cast(f16x8, wreg[ks * 8 + nf * 2]);
                f16x8 wm = __builtin_bit_cast(f16x8, wreg[ks * 8 + nf * 2 + 1]);
                acc1[nf] = __builtin_amdgcn_mfma_f32_16x16x32_f16(
                    ah, wh, acc1[nf], 0, 0, 0);
                acc2[nf] = __builtin_amdgcn_mfma_f32_16x16x32_f16(
                    ah, wm, acc2[nf], 0, 0, 0);
                acc2[nf] = __builtin_amdgcn_mfma_f32_16x16x32_f16(
                    am, wh, acc2[nf], 0, 0, 0);
            }
            __builtin_amdgcn_s_setprio(0);
        }
    };

    // ---- barrier-free K loop, static A/B x register sets ----
    float4 xA[4], xB[4];
    loadX(0, xA);
    for (int c = 0; c < NCH; c += 2) {
        if (c + 1 < NCH) loadX(c + 1, xB);
        computeChunk(c, xA);
        if (c + 2 < NCH) loadX(c + 2, xA);
        computeChunk(c + 1, xB);
    }

    // ---- epilogue: logits -> LDS (C/D: col=lane&15 -> expert,
    // row=(lane>>4)*4+reg -> token) ----
    float bb[4];
#pragma unroll
    for (int nf = 0; nf < 4; ++nf) bb[nf] = b[eh * 64 + nf * 16 + (lane & 15)];
#pragma unroll
    for (int nf = 0; nf < 4; ++nf)
#pragma unroll
        for (int r = 0; r < 4; ++r) {
            int t = tg * 16 + (lane >> 4) * 4 + r;
            int e = eh * 64 + nf * 16 + (lane & 15);
            lg[t * 132 + e] =
                fmaf(acc2[nf][r], 0.000244140625f, acc1[nf][r]) + bb[nf];
        }
    __syncthreads();

    // ---- partial top-8: 8 threads per token, 16 experts each ----
    {
        int tt = tid >> 3, p = tid & 7;
        float vals[8]; int idxs[8];
#pragma unroll
        for (int k = 0; k < 8; ++k) { vals[k] = -FLT_MAX; idxs[k] = 0; }
        const float* row = &lg[tt * 132 + p * 16];
#pragma unroll
        for (int q = 0; q < 16; ++q)
            insert8(vals, idxs, row[q], p * 16 + q);
#pragma unroll
        for (int k = 0; k < 8; ++k) {
            plv[tid * 8 + k] = vals[k];
            pli[tid * 8 + k] = idxs[k];
        }
    }
    __syncthreads();

    // ---- merge + softmax + index output (1 thread per token) ----
    float g[8]; int fidx[8];
    const bool active = (tid < MB);
    if (active) {
        float vals[8]; int idxs[8];
#pragma unroll
        for (int k = 0; k < 8; ++k) { vals[k] = -FLT_MAX; idxs[k] = 0; }
        for (int p = 0; p < 8; ++p) {
#pragma unroll
            for (int k = 0; k < 8; ++k)
                insert8(vals, idxs, plv[(tid * 8 + p) * 8 + k], pli[(tid * 8 + p) * 8 + k]);
        }
        float mx = vals[0];
        float s = 0.0f;
#pragma unroll
        for (int k = 0; k < 8; ++k) { g[k] = __expf(vals[k] - mx); s += g[k]; }
        float inv = 1.0f / s;
#pragma unroll
        for (int k = 0; k < 8; ++k) { g[k] *= inv; fidx[k] = idxs[k]; }
        // indices written as float values (whole out buffer is read back as f32)
#pragma unroll
        for (int k = 0; k < 8; ++k)
            out_idx[(size_t)(tok0 + tid) * KTOP + k] = (float)idxs[k];
    }
    // zero dense gate rows (merge no longer reads lg)
    for (int f = tid; f < MB * 132; f += NTHR) lg[f] = 0.0f;
    __syncthreads();

    if (active) {
#pragma unroll
        for (int k = 0; k < 8; ++k) lg[tid * 132 + fidx[k]] = g[k];
    }
    __syncthreads();

    // ---- coalesced dense copy-out ----
    for (int f = tid; f < MB * (NEXP / 4); f += NTHR) {
        int m = f >> 5, e4 = f & 31;
        float4 v = *(const float4*)&lg[m * 132 + e4 * 4];
        ((float4*)out_gates)[(size_t)(tok0 + m) * (NEXP / 4) + e4] = v;
    }
}

extern "C" void kernel_launch(void* const* d_in, const int* in_sizes, int n_in,
                              void* d_out, int out_size, void* d_ws, size_t ws_size,
                              hipStream_t stream) {
    const float* x = (const float*)d_in[0];   // [B,N,D] f32
    const float* W = (const float*)d_in[1];   // [E,D]   f32
    const float* b = (const float*)d_in[2];   // [E]     f32

    float* out_gates = (float*)d_out;                       // [B,N,E] f32
    float* out_idx   = out_gates + (size_t)TOKENS * NEXP;   // [B,N,K] as f32

    uint4* wf = (uint4*)d_ws;   // 1 MB: W fp16 h/m fragment tables

    wfrag_kernel<<<dim3(WFRAG_N / 256), dim3(256), 0, stream>>>(W, wf);
    router_kernel<<<dim3(TOKENS / MB), dim3(NTHR), 0, stream>>>(x, wf, b, out_gates, out_idx);
}

// Round 17
// 53.859 us; speedup vs baseline: 1.6148x; 1.6148x over previous
//
#include <hip/hip_runtime.h>
#include <cfloat>

#define TOKENS 16384   // B*N
#define DDIM   2048
#define NEXP   128
#define KTOP   8
#define MB     64      // tokens per block
#define CH     64      // k elements per chunk
#define NCH    (DDIM / CH)   // 32
#define NTHR   512     // 8 waves/block, grid 256 -> 1 block/CU

typedef float    f32x4 __attribute__((ext_vector_type(4)));
typedef _Float16 f16x8 __attribute__((ext_vector_type(8)));

// W fragment tables in d_ws (rebuilt each launch):
//   WFH[((eb*NCH + c)*2 + ks)*64 + lane] : uint4 = 8 fp16  wh = fp16(w)
//   WFM = WFH + WFRAG_N                 : 8 fp16  wm = fp16((w - wh)*4096)
// Slot j of lane l holds k = c*64 + ks*32 + (l>>4)*8 + j, expert = eb*16 + (l&15).
#define WFRAG_N (8 * NCH * 2 * 64)   // 32768 uint4 per table (512 KB)

__device__ __forceinline__ unsigned short f16bits(float f) {
    _Float16 h = (_Float16)f;                      // RNE
    return __builtin_bit_cast(unsigned short, h);
}
__device__ __forceinline__ float f16tof(unsigned short u) {
    return (float)__builtin_bit_cast(_Float16, u); // exact
}

__global__ __launch_bounds__(256, 1) void wfrag_kernel(
    const float* __restrict__ W, uint4* __restrict__ wf)
{
    int id   = blockIdx.x * 256 + threadIdx.x;   // 0..32767
    int lane = id & 63;
    int ks   = (id >> 6) & 1;
    int c    = (id >> 7) & (NCH - 1);
    int eb   = id >> 12;
    int e    = eb * 16 + (lane & 15);
    int k0   = c * CH + ks * 32 + (lane >> 4) * 8;
    const float* src = W + (size_t)e * DDIM + k0;
    unsigned hw[4], mw[4];
#pragma unroll
    for (int p = 0; p < 4; ++p) {
        float f0 = src[2 * p], f1 = src[2 * p + 1];
        unsigned short h0 = f16bits(f0), h1 = f16bits(f1);
        unsigned short m0 = f16bits((f0 - f16tof(h0)) * 4096.0f);
        unsigned short m1 = f16bits((f1 - f16tof(h1)) * 4096.0f);
        hw[p] = (unsigned)h0 | ((unsigned)h1 << 16);
        mw[p] = (unsigned)m0 | ((unsigned)m1 << 16);
    }
    wf[id]           = make_uint4(hw[0], hw[1], hw[2], hw[3]);
    wf[WFRAG_N + id] = make_uint4(mw[0], mw[1], mw[2], mw[3]);
}

// branchless sorted-insert into descending top-8 list.
// strict '>' => ties keep the earlier (lower) index, matching jax.lax.top_k.
__device__ __forceinline__ void insert8(float (&vals)[8], int (&idxs)[8], float v, int e) {
    bool c[8];
#pragma unroll
    for (int p = 0; p < 8; ++p) c[p] = v > vals[p];
#pragma unroll
    for (int p = 7; p >= 1; --p) {
        vals[p] = c[p] ? (c[p - 1] ? vals[p - 1] : v) : vals[p];
        idxs[p] = c[p] ? (c[p - 1] ? idxs[p - 1] : e) : idxs[p];
    }
    vals[0] = c[0] ? v : vals[0];
    idxs[0] = c[0] ? e : idxs[0];
}

// fp16-split MFMA router = R12 structure + 4-deep x register prefetch.
// R10-R16 falsified occupancy/traffic/barrier theories; surviving model:
// x delivery is latency*MLP-bound (2-deep prefetch -> ~16KB/CU outstanding
// -> ~2TB/s -> 134MB x = ~60us, the invariant). This round doubles x MLP:
// named sets S0..S3, unroll-4 (static indexing), x(c+4) issued at chunk c;
// lgkm-only barrier (R13) so the loads survive the barrier.
// Per-logit MFMA sequence unchanged -> bit-identical logits -> same indices.
__device__ __forceinline__ void chunk_barrier() {
    asm volatile("s_waitcnt lgkmcnt(0)" ::: "memory");
    __builtin_amdgcn_sched_barrier(0);
    __builtin_amdgcn_s_barrier();
    __builtin_amdgcn_sched_barrier(0);
}

__global__ __launch_bounds__(NTHR, 1) void router_kernel(
    const float* __restrict__ x, const uint4* __restrict__ wf,
    const float* __restrict__ b, float* __restrict__ out_gates,
    float* __restrict__ out_idx)
{
    // GEMM phase: xh dbuf @0,8192; xm dbuf @16384,24576 (32 KB total)
    // Epilogue overlay: lg [64][132] f32 @0 (33792);
    //   plv [256 lists][stride 9] f32 @33792 (9216); pli @43008 (9216)
    __shared__ __align__(16) char smem[52224];
    float* lg  = (float*)smem;
    float* plv = (float*)(smem + 33792);
    int*   pli = (int*)(smem + 43008);

    const int tid  = threadIdx.x;
    const int lane = tid & 63;
    const int wid  = tid >> 6;           // wave 0..7 -> expert-block eb = wid
    const int tok0 = blockIdx.x * MB;

    const uint4* WFH = wf;
    const uint4* WFM = wf + WFRAG_N;

    f32x4 acc1[4], acc2[4];              // [mf] -> tokens 16*mf..16*mf+15
#pragma unroll
    for (int mf = 0; mf < 4; ++mf) {
        acc1[mf] = (f32x4){0.f, 0.f, 0.f, 0.f};
        acc2[mf] = (f32x4){0.f, 0.f, 0.f, 0.f};
    }

    const float4* x4 = (const float4*)x;
    // x staging: 512 threads stage 64 rows x 16 float4-cols (2 per thread)
    const int xr0 = tid >> 4, xr1 = 32 + (tid >> 4), xq = tid & 15;
    const size_t xoff0 = (size_t)(tok0 + xr0) * (DDIM / 4) + xq;
    const size_t xoff1 = (size_t)(tok0 + xr1) * (DDIM / 4) + xq;
    // swizzled LDS byte offsets (16B-slot ^= row&7); 8 B (4 fp16) per write
    const int xb0 = xr0 * 128 + (((xq >> 1) ^ (xr0 & 7)) << 4) + (xq & 1) * 8;
    const int xb1 = xr1 * 128 + (((xq >> 1) ^ (xr1 & 7)) << 4) + (xq & 1) * 8;

    float4 S0[2], S1[2], S2[2], S3[2];   // 4-deep x pipeline (named, static)
    uint4  wA[4], wB[4];                 // [0..1]=wh (ks), [2..3]=wm (ks)

    auto loadX = [&](int c, float4 (&S)[2]) {
        S[0] = x4[xoff0 + (size_t)c * 16];
        S[1] = x4[xoff1 + (size_t)c * 16];
    };
    auto loadW = [&](int c, uint4 (&wreg)[4]) {
#pragma unroll
        for (int ks = 0; ks < 2; ++ks) {
            int idx = ((wid * NCH + c) * 2 + ks) * 64 + lane;
            wreg[ks]     = WFH[idx];
            wreg[2 + ks] = WFM[idx];
        }
    };
    auto convertX = [&](const float4 (&sx)[2], char* ldsDst) {
#pragma unroll
        for (int r = 0; r < 2; ++r) {
            const float4 v = sx[r];
            unsigned short h0 = f16bits(v.x), h1 = f16bits(v.y);
            unsigned short h2 = f16bits(v.z), h3 = f16bits(v.w);
            unsigned short m0 = f16bits((v.x - f16tof(h0)) * 4096.0f);
            unsigned short m1 = f16bits((v.y - f16tof(h1)) * 4096.0f);
            unsigned short m2 = f16bits((v.z - f16tof(h2)) * 4096.0f);
            unsigned short m3 = f16bits((v.w - f16tof(h3)) * 4096.0f);
            uint2 hv = make_uint2((unsigned)h0 | ((unsigned)h1 << 16),
                                  (unsigned)h2 | ((unsigned)h3 << 16));
            uint2 mv = make_uint2((unsigned)m0 | ((unsigned)m1 << 16),
                                  (unsigned)m2 | ((unsigned)m3 << 16));
            const int byteoff = r ? xb1 : xb0;
            *(uint2*)(ldsDst + byteoff)         = hv;
            *(uint2*)(ldsDst + 16384 + byteoff) = mv;
        }
    };

    // step at chunk c: issue x(c+4) into Sload (freed last chunk), issue
    // W(c+1), MFMA chunk c, convert Scvt (= x(c+1)) into the other buffer.
    auto step = [&](int c, float4 (&Sload)[2], float4 (&Scvt)[2],
                    uint4 (&wCur)[4], uint4 (&wNext)[4],
                    char* bufCur, char* bufNext) {
        if (c + 4 < NCH) loadX(c + 4, Sload);
        if (c + 1 < NCH) loadW(c + 1, wNext);

        // compute chunk c: 16 ds_read_b128 + 24 MFMAs per wave
#pragma unroll
        for (int ks = 0; ks < 2; ++ks) {
            f16x8 ah[4], am[4];
#pragma unroll
            for (int mf = 0; mf < 4; ++mf) {
                int row = 16 * mf + (lane & 15);
                int byteoff = row * 128 +
                    ((((ks << 2) | (lane >> 4)) ^ (row & 7)) << 4);
                ah[mf] = *(const f16x8*)(bufCur + byteoff);
                am[mf] = *(const f16x8*)(bufCur + 16384 + byteoff);
            }
            f16x8 wh = __builtin_bit_cast(f16x8, wCur[ks]);
            f16x8 wm = __builtin_bit_cast(f16x8, wCur[2 + ks]);
#pragma unroll
            for (int mf = 0; mf < 4; ++mf) {
                acc1[mf] = __builtin_amdgcn_mfma_f32_16x16x32_f16(
                    ah[mf], wh, acc1[mf], 0, 0, 0);
                acc2[mf] = __builtin_amdgcn_mfma_f32_16x16x32_f16(
                    ah[mf], wm, acc2[mf], 0, 0, 0);
                acc2[mf] = __builtin_amdgcn_mfma_f32_16x16x32_f16(
                    am[mf], wh, acc2[mf], 0, 0, 0);
            }
        }

        if (c + 1 < NCH) convertX(Scvt, bufNext);
        chunk_barrier();
    };

    // ---- prologue: x(0..3) in S0..S3, W(0); convert x(0) -> buf0 ----
    loadX(0, S0);
    loadX(1, S1);
    loadW(0, wA);
    loadX(2, S2);
    loadX(3, S3);
    convertX(S0, smem);
    chunk_barrier();

    char* buf0 = smem;
    char* buf1 = smem + 8192;
    for (int cc = 0; cc < NCH; cc += 4) {
        step(cc,     S0, S1, wA, wB, buf0, buf1);
        step(cc + 1, S1, S2, wB, wA, buf1, buf0);
        step(cc + 2, S2, S3, wA, wB, buf0, buf1);
        step(cc + 3, S3, S0, wB, wA, buf1, buf0);
    }

    // ---- epilogue: logits -> LDS (C/D: col=lane&15 -> expert,
    // row=(lane>>4)*4+reg -> token) ----
    const float bb = b[wid * 16 + (lane & 15)];
#pragma unroll
    for (int mf = 0; mf < 4; ++mf)
#pragma unroll
        for (int r = 0; r < 4; ++r) {
            int t = 16 * mf + (lane >> 4) * 4 + r;
            int e = wid * 16 + (lane & 15);
            lg[t * 132 + e] =
                fmaf(acc2[mf][r], 0.000244140625f, acc1[mf][r]) + bb;
        }
    __syncthreads();

    // ---- partial top-8: 4 threads per token, 32 experts each (R0 pattern) ----
    if (tid < 256) {
        int tt = tid >> 2, p = tid & 3;
        float vals[8]; int idxs[8];
#pragma unroll
        for (int k = 0; k < 8; ++k) { vals[k] = -FLT_MAX; idxs[k] = 0; }
        const float* row = &lg[tt * 132 + p * 32];
        for (int q = 0; q < 32; ++q)
            insert8(vals, idxs, row[q], p * 32 + q);
#pragma unroll
        for (int k = 0; k < 8; ++k) {
            plv[tid * 9 + k] = vals[k];   // stride 9: break merge bank conflict
            pli[tid * 9 + k] = idxs[k];
        }
    }
    __syncthreads();

    // ---- merge + softmax + index output (1 thread per token) ----
    float g[8]; int fidx[8];
    const bool active = (tid < MB);
    if (active) {
        float vals[8]; int idxs[8];
#pragma unroll
        for (int k = 0; k < 8; ++k) { vals[k] = -FLT_MAX; idxs[k] = 0; }
        for (int p = 0; p < 4; ++p) {
#pragma unroll
            for (int k = 0; k < 8; ++k)
                insert8(vals, idxs, plv[(tid * 4 + p) * 9 + k], pli[(tid * 4 + p) * 9 + k]);
        }
        float mx = vals[0];
        float s = 0.0f;
#pragma unroll
        for (int k = 0; k < 8; ++k) { g[k] = __expf(vals[k] - mx); s += g[k]; }
        float inv = 1.0f / s;
#pragma unroll
        for (int k = 0; k < 8; ++k) { g[k] *= inv; fidx[k] = idxs[k]; }
        // indices written as float values (whole out buffer is read back as f32)
#pragma unroll
        for (int k = 0; k < 8; ++k)
            out_idx[(size_t)(tok0 + tid) * KTOP + k] = (float)idxs[k];
    }
    // zero dense gate rows (merge no longer reads lg)
    for (int f = tid; f < MB * 132; f += NTHR) lg[f] = 0.0f;
    __syncthreads();

    if (active) {
#pragma unroll
        for (int k = 0; k < 8; ++k) lg[tid * 132 + fidx[k]] = g[k];
    }
    __syncthreads();

    // ---- coalesced dense copy-out ----
    for (int f = tid; f < MB * (NEXP / 4); f += NTHR) {
        int m = f >> 5, e4 = f & 31;
        float4 v = *(const float4*)&lg[m * 132 + e4 * 4];
        ((float4*)out_gates)[(size_t)(tok0 + m) * (NEXP / 4) + e4] = v;
    }
}

extern "C" void kernel_launch(void* const* d_in, const int* in_sizes, int n_in,
                              void* d_out, int out_size, void* d_ws, size_t ws_size,
                              hipStream_t stream) {
    const float* x = (const float*)d_in[0];   // [B,N,D] f32
    const float* W = (const float*)d_in[1];   // [E,D]   f32
    const float* b = (const float*)d_in[2];   // [E]     f32

    float* out_gates = (float*)d_out;                       // [B,N,E] f32
    float* out_idx   = out_gates + (size_t)TOKENS * NEXP;   // [B,N,K] as f32

    uint4* wf = (uint4*)d_ws;   // 1 MB: W fp16 h/m fragment tables

    wfrag_kernel<<<dim3(WFRAG_N / 256), dim3(256), 0, stream>>>(W, wf);
    router_kernel<<<dim3(TOKENS / MB), dim3(NTHR), 0, stream>>>(x, wf, b, out_gates, out_idx);
}

// Round 18
// 53.372 us; speedup vs baseline: 1.6295x; 1.0091x over previous
//
#include <hip/hip_runtime.h>
#include <cfloat>

#define TOKENS 16384   // B*N
#define DDIM   2048
#define NEXP   128
#define KTOP   8
#define MB     64      // tokens per block
#define CH     64      // k elements per chunk
#define NCH    (DDIM / CH)   // 32
#define NTHR   512     // 8 waves/block, grid 256 -> 1 block/CU

typedef float    f32x4 __attribute__((ext_vector_type(4)));
typedef _Float16 f16x8 __attribute__((ext_vector_type(8)));

// W fragment tables in d_ws (rebuilt each launch):
//   WFH[((eb*NCH + c)*2 + ks)*64 + lane] : uint4 = 8 fp16  wh = fp16(w)
//   WFM = WFH + WFRAG_N                 : 8 fp16  wm = fp16((w - wh)*4096)
// Slot j of lane l holds k = c*64 + ks*32 + (l>>4)*8 + j, expert = eb*16 + (l&15).
#define WFRAG_N (8 * NCH * 2 * 64)   // 32768 uint4 per table (512 KB)

__device__ __forceinline__ unsigned short f16bits(float f) {
    _Float16 h = (_Float16)f;                      // RNE
    return __builtin_bit_cast(unsigned short, h);
}
__device__ __forceinline__ float f16tof(unsigned short u) {
    return (float)__builtin_bit_cast(_Float16, u); // exact
}

__global__ __launch_bounds__(256, 1) void wfrag_kernel(
    const float* __restrict__ W, uint4* __restrict__ wf)
{
    int id   = blockIdx.x * 256 + threadIdx.x;   // 0..32767
    int lane = id & 63;
    int ks   = (id >> 6) & 1;
    int c    = (id >> 7) & (NCH - 1);
    int eb   = id >> 12;
    int e    = eb * 16 + (lane & 15);
    int k0   = c * CH + ks * 32 + (lane >> 4) * 8;
    const float* src = W + (size_t)e * DDIM + k0;
    unsigned hw[4], mw[4];
#pragma unroll
    for (int p = 0; p < 4; ++p) {
        float f0 = src[2 * p], f1 = src[2 * p + 1];
        unsigned short h0 = f16bits(f0), h1 = f16bits(f1);
        unsigned short m0 = f16bits((f0 - f16tof(h0)) * 4096.0f);
        unsigned short m1 = f16bits((f1 - f16tof(h1)) * 4096.0f);
        hw[p] = (unsigned)h0 | ((unsigned)h1 << 16);
        mw[p] = (unsigned)m0 | ((unsigned)m1 << 16);
    }
    wf[id]           = make_uint4(hw[0], hw[1], hw[2], hw[3]);
    wf[WFRAG_N + id] = make_uint4(mw[0], mw[1], mw[2], mw[3]);
}

// branchless sorted-insert into descending top-8 list.
// strict '>' => ties keep the earlier (lower) index, matching jax.lax.top_k.
__device__ __forceinline__ void insert8(float (&vals)[8], int (&idxs)[8], float v, int e) {
    bool c[8];
#pragma unroll
    for (int p = 0; p < 8; ++p) c[p] = v > vals[p];
#pragma unroll
    for (int p = 7; p >= 1; --p) {
        vals[p] = c[p] ? (c[p - 1] ? vals[p - 1] : v) : vals[p];
        idxs[p] = c[p] ? (c[p - 1] ? idxs[p - 1] : e) : idxs[p];
    }
    vals[0] = c[0] ? v : vals[0];
    idxs[0] = c[0] ? e : idxs[0];
}

// fp16-split MFMA router = R17 structure with the x register pipeline
// deepened 4 -> 8 (S0..S7, full unroll-8, static indexing; x(c+8) issued at
// chunk c). R17 confirmed the x latency*MLP model: depth 2->4 gave
// 62.2 -> 53.9us. Outstanding x per CU doubles again (~32KB).
// Per-logit MFMA sequence unchanged -> bit-identical logits -> same indices.
__device__ __forceinline__ void chunk_barrier() {
    asm volatile("s_waitcnt lgkmcnt(0)" ::: "memory");
    __builtin_amdgcn_sched_barrier(0);
    __builtin_amdgcn_s_barrier();
    __builtin_amdgcn_sched_barrier(0);
}

__global__ __launch_bounds__(NTHR, 1) void router_kernel(
    const float* __restrict__ x, const uint4* __restrict__ wf,
    const float* __restrict__ b, float* __restrict__ out_gates,
    float* __restrict__ out_idx)
{
    // GEMM phase: xh dbuf @0,8192; xm dbuf @16384,24576 (32 KB total)
    // Epilogue overlay: lg [64][132] f32 @0 (33792);
    //   plv [256 lists][stride 9] f32 @33792 (9216); pli @43008 (9216)
    __shared__ __align__(16) char smem[52224];
    float* lg  = (float*)smem;
    float* plv = (float*)(smem + 33792);
    int*   pli = (int*)(smem + 43008);

    const int tid  = threadIdx.x;
    const int lane = tid & 63;
    const int wid  = tid >> 6;           // wave 0..7 -> expert-block eb = wid
    const int tok0 = blockIdx.x * MB;

    const uint4* WFH = wf;
    const uint4* WFM = wf + WFRAG_N;

    f32x4 acc1[4], acc2[4];              // [mf] -> tokens 16*mf..16*mf+15
#pragma unroll
    for (int mf = 0; mf < 4; ++mf) {
        acc1[mf] = (f32x4){0.f, 0.f, 0.f, 0.f};
        acc2[mf] = (f32x4){0.f, 0.f, 0.f, 0.f};
    }

    const float4* x4 = (const float4*)x;
    // x staging: 512 threads stage 64 rows x 16 float4-cols (2 per thread)
    const int xr0 = tid >> 4, xr1 = 32 + (tid >> 4), xq = tid & 15;
    const size_t xoff0 = (size_t)(tok0 + xr0) * (DDIM / 4) + xq;
    const size_t xoff1 = (size_t)(tok0 + xr1) * (DDIM / 4) + xq;
    // swizzled LDS byte offsets (16B-slot ^= row&7); 8 B (4 fp16) per write
    const int xb0 = xr0 * 128 + (((xq >> 1) ^ (xr0 & 7)) << 4) + (xq & 1) * 8;
    const int xb1 = xr1 * 128 + (((xq >> 1) ^ (xr1 & 7)) << 4) + (xq & 1) * 8;

    // 8-deep x pipeline (named, static indexing)
    float4 S0[2], S1[2], S2[2], S3[2], S4[2], S5[2], S6[2], S7[2];
    uint4  wA[4], wB[4];                 // [0..1]=wh (ks), [2..3]=wm (ks)

    auto loadX = [&](int c, float4 (&S)[2]) {
        S[0] = x4[xoff0 + (size_t)c * 16];
        S[1] = x4[xoff1 + (size_t)c * 16];
    };
    auto loadW = [&](int c, uint4 (&wreg)[4]) {
#pragma unroll
        for (int ks = 0; ks < 2; ++ks) {
            int idx = ((wid * NCH + c) * 2 + ks) * 64 + lane;
            wreg[ks]     = WFH[idx];
            wreg[2 + ks] = WFM[idx];
        }
    };
    auto convertX = [&](const float4 (&sx)[2], char* ldsDst) {
#pragma unroll
        for (int r = 0; r < 2; ++r) {
            const float4 v = sx[r];
            unsigned short h0 = f16bits(v.x), h1 = f16bits(v.y);
            unsigned short h2 = f16bits(v.z), h3 = f16bits(v.w);
            unsigned short m0 = f16bits((v.x - f16tof(h0)) * 4096.0f);
            unsigned short m1 = f16bits((v.y - f16tof(h1)) * 4096.0f);
            unsigned short m2 = f16bits((v.z - f16tof(h2)) * 4096.0f);
            unsigned short m3 = f16bits((v.w - f16tof(h3)) * 4096.0f);
            uint2 hv = make_uint2((unsigned)h0 | ((unsigned)h1 << 16),
                                  (unsigned)h2 | ((unsigned)h3 << 16));
            uint2 mv = make_uint2((unsigned)m0 | ((unsigned)m1 << 16),
                                  (unsigned)m2 | ((unsigned)m3 << 16));
            const int byteoff = r ? xb1 : xb0;
            *(uint2*)(ldsDst + byteoff)         = hv;
            *(uint2*)(ldsDst + 16384 + byteoff) = mv;
        }
    };

    // step at chunk c: issue x(c+8) into Sload (converted last chunk), issue
    // W(c+1), MFMA chunk c, convert Scvt (= x(c+1)) into the other buffer.
    auto step = [&](int c, float4 (&Sload)[2], float4 (&Scvt)[2],
                    uint4 (&wCur)[4], uint4 (&wNext)[4],
                    char* bufCur, char* bufNext) {
        if (c + 8 < NCH) loadX(c + 8, Sload);
        if (c + 1 < NCH) loadW(c + 1, wNext);

        // compute chunk c: 16 ds_read_b128 + 24 MFMAs per wave
#pragma unroll
        for (int ks = 0; ks < 2; ++ks) {
            f16x8 ah[4], am[4];
#pragma unroll
            for (int mf = 0; mf < 4; ++mf) {
                int row = 16 * mf + (lane & 15);
                int byteoff = row * 128 +
                    ((((ks << 2) | (lane >> 4)) ^ (row & 7)) << 4);
                ah[mf] = *(const f16x8*)(bufCur + byteoff);
                am[mf] = *(const f16x8*)(bufCur + 16384 + byteoff);
            }
            f16x8 wh = __builtin_bit_cast(f16x8, wCur[ks]);
            f16x8 wm = __builtin_bit_cast(f16x8, wCur[2 + ks]);
#pragma unroll
            for (int mf = 0; mf < 4; ++mf) {
                acc1[mf] = __builtin_amdgcn_mfma_f32_16x16x32_f16(
                    ah[mf], wh, acc1[mf], 0, 0, 0);
                acc2[mf] = __builtin_amdgcn_mfma_f32_16x16x32_f16(
                    ah[mf], wm, acc2[mf], 0, 0, 0);
                acc2[mf] = __builtin_amdgcn_mfma_f32_16x16x32_f16(
                    am[mf], wh, acc2[mf], 0, 0, 0);
            }
        }

        if (c + 1 < NCH) convertX(Scvt, bufNext);
        chunk_barrier();
    };

    // ---- prologue: x(0..7) in S0..S7, W(0); convert x(0) -> buf0 ----
    loadX(0, S0);
    loadX(1, S1);
    loadW(0, wA);
    loadX(2, S2);
    loadX(3, S3);
    loadX(4, S4);
    loadX(5, S5);
    loadX(6, S6);
    loadX(7, S7);
    convertX(S0, smem);
    chunk_barrier();

    char* buf0 = smem;
    char* buf1 = smem + 8192;
    for (int cc = 0; cc < NCH; cc += 8) {
        step(cc,     S0, S1, wA, wB, buf0, buf1);
        step(cc + 1, S1, S2, wB, wA, buf1, buf0);
        step(cc + 2, S2, S3, wA, wB, buf0, buf1);
        step(cc + 3, S3, S4, wB, wA, buf1, buf0);
        step(cc + 4, S4, S5, wA, wB, buf0, buf1);
        step(cc + 5, S5, S6, wB, wA, buf1, buf0);
        step(cc + 6, S6, S7, wA, wB, buf0, buf1);
        step(cc + 7, S7, S0, wB, wA, buf1, buf0);
    }

    // ---- epilogue: logits -> LDS (C/D: col=lane&15 -> expert,
    // row=(lane>>4)*4+reg -> token) ----
    const float bb = b[wid * 16 + (lane & 15)];
#pragma unroll
    for (int mf = 0; mf < 4; ++mf)
#pragma unroll
        for (int r = 0; r < 4; ++r) {
            int t = 16 * mf + (lane >> 4) * 4 + r;
            int e = wid * 16 + (lane & 15);
            lg[t * 132 + e] =
                fmaf(acc2[mf][r], 0.000244140625f, acc1[mf][r]) + bb;
        }
    __syncthreads();

    // ---- partial top-8: 4 threads per token, 32 experts each (R0 pattern) ----
    if (tid < 256) {
        int tt = tid >> 2, p = tid & 3;
        float vals[8]; int idxs[8];
#pragma unroll
        for (int k = 0; k < 8; ++k) { vals[k] = -FLT_MAX; idxs[k] = 0; }
        const float* row = &lg[tt * 132 + p * 32];
        for (int q = 0; q < 32; ++q)
            insert8(vals, idxs, row[q], p * 32 + q);
#pragma unroll
        for (int k = 0; k < 8; ++k) {
            plv[tid * 9 + k] = vals[k];   // stride 9: break merge bank conflict
            pli[tid * 9 + k] = idxs[k];
        }
    }
    __syncthreads();

    // ---- merge + softmax + index output (1 thread per token) ----
    float g[8]; int fidx[8];
    const bool active = (tid < MB);
    if (active) {
        float vals[8]; int idxs[8];
#pragma unroll
        for (int k = 0; k < 8; ++k) { vals[k] = -FLT_MAX; idxs[k] = 0; }
        for (int p = 0; p < 4; ++p) {
#pragma unroll
            for (int k = 0; k < 8; ++k)
                insert8(vals, idxs, plv[(tid * 4 + p) * 9 + k], pli[(tid * 4 + p) * 9 + k]);
        }
        float mx = vals[0];
        float s = 0.0f;
#pragma unroll
        for (int k = 0; k < 8; ++k) { g[k] = __expf(vals[k] - mx); s += g[k]; }
        float inv = 1.0f / s;
#pragma unroll
        for (int k = 0; k < 8; ++k) { g[k] *= inv; fidx[k] = idxs[k]; }
        // indices written as float values (whole out buffer is read back as f32)
#pragma unroll
        for (int k = 0; k < 8; ++k)
            out_idx[(size_t)(tok0 + tid) * KTOP + k] = (float)idxs[k];
    }
    // zero dense gate rows (merge no longer reads lg)
    for (int f = tid; f < MB * 132; f += NTHR) lg[f] = 0.0f;
    __syncthreads();

    if (active) {
#pragma unroll
        for (int k = 0; k < 8; ++k) lg[tid * 132 + fidx[k]] = g[k];
    }
    __syncthreads();

    // ---- coalesced dense copy-out ----
    for (int f = tid; f < MB * (NEXP / 4); f += NTHR) {
        int m = f >> 5, e4 = f & 31;
        float4 v = *(const float4*)&lg[m * 132 + e4 * 4];
        ((float4*)out_gates)[(size_t)(tok0 + m) * (NEXP / 4) + e4] = v;
    }
}

extern "C" void kernel_launch(void* const* d_in, const int* in_sizes, int n_in,
                              void* d_out, int out_size, void* d_ws, size_t ws_size,
                              hipStream_t stream) {
    const float* x = (const float*)d_in[0];   // [B,N,D] f32
    const float* W = (const float*)d_in[1];   // [E,D]   f32
    const float* b = (const float*)d_in[2];   // [E]     f32

    float* out_gates = (float*)d_out;                       // [B,N,E] f32
    float* out_idx   = out_gates + (size_t)TOKENS * NEXP;   // [B,N,K] as f32

    uint4* wf = (uint4*)d_ws;   // 1 MB: W fp16 h/m fragment tables

    wfrag_kernel<<<dim3(WFRAG_N / 256), dim3(256), 0, stream>>>(W, wf);
    router_kernel<<<dim3(TOKENS / MB), dim3(NTHR), 0, stream>>>(x, wf, b, out_gates, out_idx);
}